// Round 1
// baseline (272.519 us; speedup 1.0000x reference)
//
#include <hip/hip_runtime.h>
#include <math.h>

// Problem constants (B,S,E) = (8, 4096, 1024), all fp32.
constexpr int Bc  = 8;
constexpr int Sc  = 4096;
constexpr int Ec  = 1024;
constexpr int BEc = Bc * Ec;   // 8192 (b,e) columns

// feature map: exact gelu (erf-based) + 1  -> always > 0.83
__device__ __forceinline__ float feat(float x) {
    return fmaf(0.5f * x, 1.0f + erff(x * 0.70710678118654752f), 1.0f);
}
__device__ __forceinline__ float4 feat4(float4 v) {
    return make_float4(feat(v.x), feat(v.y), feat(v.z), feat(v.w));
}

// K1: per-(b,e) partial colsum(qf*kf), max(qf), min(qf) over an s-chunk.
// grid = (NS, B), block = 256 threads, each thread owns 4 consecutive e.
__global__ void __launch_bounds__(256)
sa_stats_part(const float* __restrict__ qp, const float* __restrict__ kp,
              float* __restrict__ psum, float* __restrict__ pmax,
              float* __restrict__ pmin, int SC) {
    const int chunk = blockIdx.x, b = blockIdx.y;
    const int e = threadIdx.x * 4;
    int base = (b * Sc + chunk * SC) * Ec + e;
    float4 s  = make_float4(0.f, 0.f, 0.f, 0.f);
    float4 mx = make_float4(-1e30f, -1e30f, -1e30f, -1e30f);
    float4 mn = make_float4( 1e30f,  1e30f,  1e30f,  1e30f);
    for (int r = 0; r < SC; ++r, base += Ec) {
        float4 qv = feat4(*(const float4*)(qp + base));
        float4 kv = feat4(*(const float4*)(kp + base));
        s.x = fmaf(qv.x, kv.x, s.x);  mx.x = fmaxf(mx.x, qv.x);  mn.x = fminf(mn.x, qv.x);
        s.y = fmaf(qv.y, kv.y, s.y);  mx.y = fmaxf(mx.y, qv.y);  mn.y = fminf(mn.y, qv.y);
        s.z = fmaf(qv.z, kv.z, s.z);  mx.z = fmaxf(mx.z, qv.z);  mn.z = fminf(mn.z, qv.z);
        s.w = fmaf(qv.w, kv.w, s.w);  mx.w = fmaxf(mx.w, qv.w);  mn.w = fminf(mn.w, qv.w);
    }
    const int o = chunk * BEc + b * Ec + e;
    *(float4*)(psum + o) = s;
    *(float4*)(pmax + o) = mx;
    *(float4*)(pmin + o) = mn;
}

// K2: finalize stats -> c[b,e] = colsum/sqrt(E); eMax = c>=0 ? c*max : c*min
__global__ void __launch_bounds__(256)
sa_stats_fin(const float* __restrict__ psum, const float* __restrict__ pmax,
             const float* __restrict__ pmin, float* __restrict__ cbuf,
             float* __restrict__ embuf, int NS) {
    const int id = blockIdx.x * blockDim.x + threadIdx.x;
    float s = 0.f, mx = -1e30f, mn = 1e30f;
    for (int ch = 0; ch < NS; ++ch) {
        s += psum[ch * BEc + id];
        mx = fmaxf(mx, pmax[ch * BEc + id]);
        mn = fminf(mn, pmin[ch * BEc + id]);
    }
    const float c = s * (1.0f / 32.0f);   // 1/sqrt(1024)
    cbuf[id]  = c;
    embuf[id] = (c >= 0.f) ? c * mx : c * mn;
}

// K3: partial softmax denominator: sum_s exp(c*qf - eMax) over an s-chunk.
__global__ void __launch_bounds__(256)
sa_den_part(const float* __restrict__ qp, const float* __restrict__ cbuf,
            const float* __restrict__ embuf, float* __restrict__ pden, int SC) {
    const int chunk = blockIdx.x, b = blockIdx.y;
    const int e = threadIdx.x * 4;
    const float4 c4 = *(const float4*)(cbuf + b * Ec + e);
    const float4 m4 = *(const float4*)(embuf + b * Ec + e);
    int base = (b * Sc + chunk * SC) * Ec + e;
    float4 d = make_float4(0.f, 0.f, 0.f, 0.f);
    for (int r = 0; r < SC; ++r, base += Ec) {
        float4 qv = feat4(*(const float4*)(qp + base));
        d.x += expf(fmaf(c4.x, qv.x, -m4.x));
        d.y += expf(fmaf(c4.y, qv.y, -m4.y));
        d.z += expf(fmaf(c4.z, qv.z, -m4.z));
        d.w += expf(fmaf(c4.w, qv.w, -m4.w));
    }
    const int o = chunk * BEc + b * Ec + e;
    *(float4*)(pden + o) = d;
}

// K4: finalize denominator -> reciprocal
__global__ void __launch_bounds__(256)
sa_den_fin(const float* __restrict__ pden, float* __restrict__ rdbuf, int NS) {
    const int id = blockIdx.x * blockDim.x + threadIdx.x;
    float s = 0.f;
    for (int ch = 0; ch < NS; ++ch) s += pden[ch * BEc + id];
    rdbuf[id] = 1.0f / s;
}

// K5: out = exp(c*qf - eMax) * rdenom * values
__global__ void __launch_bounds__(256)
sa_out(const float* __restrict__ qp, const float* __restrict__ vp,
       const float* __restrict__ cbuf, const float* __restrict__ embuf,
       const float* __restrict__ rdbuf, float* __restrict__ outp, int SC) {
    const int chunk = blockIdx.x, b = blockIdx.y;
    const int e = threadIdx.x * 4;
    const float4 c4 = *(const float4*)(cbuf + b * Ec + e);
    const float4 m4 = *(const float4*)(embuf + b * Ec + e);
    const float4 r4 = *(const float4*)(rdbuf + b * Ec + e);
    int base = (b * Sc + chunk * SC) * Ec + e;
    for (int r = 0; r < SC; ++r, base += Ec) {
        float4 qv = feat4(*(const float4*)(qp + base));
        float4 vv = *(const float4*)(vp + base);
        float4 o;
        o.x = expf(fmaf(c4.x, qv.x, -m4.x)) * r4.x * vv.x;
        o.y = expf(fmaf(c4.y, qv.y, -m4.y)) * r4.y * vv.y;
        o.z = expf(fmaf(c4.z, qv.z, -m4.z)) * r4.z * vv.z;
        o.w = expf(fmaf(c4.w, qv.w, -m4.w)) * r4.w * vv.w;
        *(float4*)(outp + base) = o;
    }
}

extern "C" void kernel_launch(void* const* d_in, const int* in_sizes, int n_in,
                              void* d_out, int out_size, void* d_ws, size_t ws_size,
                              hipStream_t stream) {
    const float* q = (const float*)d_in[0];
    const float* k = (const float*)d_in[1];
    const float* v = (const float*)d_in[2];
    float* out = (float*)d_out;

    // pick the largest s-chunk count that fits the workspace
    int NS = 128;
    while (NS > 1 &&
           (size_t)(3u * NS * BEc + 3u * BEc) * sizeof(float) > ws_size)
        NS >>= 1;
    const int SC = Sc / NS;

    float* w     = (float*)d_ws;
    float* psum  = w;
    float* pmax  = psum + (size_t)NS * BEc;
    float* pmin  = pmax + (size_t)NS * BEc;
    float* pden  = psum;                      // reused after sa_stats_fin
    float* cbuf  = pmin + (size_t)NS * BEc;
    float* embuf = cbuf + BEc;
    float* rdbuf = embuf + BEc;

    dim3 gridP(NS, Bc);
    sa_stats_part<<<gridP, 256, 0, stream>>>(q, k, psum, pmax, pmin, SC);
    sa_stats_fin<<<BEc / 256, 256, 0, stream>>>(psum, pmax, pmin, cbuf, embuf, NS);
    sa_den_part<<<gridP, 256, 0, stream>>>(q, cbuf, embuf, pden, SC);
    sa_den_fin<<<BEc / 256, 256, 0, stream>>>(pden, rdbuf, NS);
    sa_out<<<gridP, 256, 0, stream>>>(q, v, cbuf, embuf, rdbuf, out, SC);
}

// Round 3
// 158.371 us; speedup vs baseline: 1.7208x; 1.7208x over previous
//
#include <hip/hip_runtime.h>
#include <math.h>

// Problem constants (B,S,E) = (8, 4096, 1024), all fp32.
constexpr int Bc  = 8;
constexpr int Sc  = 4096;
constexpr int Ec  = 1024;
constexpr int BEc = Bc * Ec;   // 8192 (b,e) columns
constexpr int NP  = 8;         // second-stage reduction parts

// native 4-wide float vector (works with nontemporal builtins)
typedef float f4 __attribute__((ext_vector_type(4)));

// fast feature map: gelu(x)+1 with A&S 7.1.26 erf (|eps| <= 1.5e-7)
// ~16 VALU ops vs ~65 for OCML erff.
__device__ __forceinline__ float fast_feat(float x) {
    float a = fabsf(x) * 0.70710678118654752f;          // |x|/sqrt(2)
    float t = __builtin_amdgcn_rcpf(fmaf(0.3275911f, a, 1.0f));
    float p = fmaf(1.061405429f, t, -1.453152027f);
    p = fmaf(p, t, 1.421413741f);
    p = fmaf(p, t, -0.284496736f);
    p = fmaf(p, t, 0.254829592f);
    float e  = __expf(-a * a);
    float er = fmaf(-p * t, e, 1.0f);                   // erf(|x|/sqrt2)
    er = copysignf(er, x);
    return fmaf(0.5f * x, 1.0f + er, 1.0f);
}
__device__ __forceinline__ f4 feat4(f4 v) {
    f4 r;
    r.x = fast_feat(v.x); r.y = fast_feat(v.y);
    r.z = fast_feat(v.z); r.w = fast_feat(v.w);
    return r;
}

// K1: per-(b,e) partial colsum(qf*kf), max(qf), min(qf) over an s-chunk.
// grid = (NS, B), block = 256 threads, each thread owns 4 consecutive e.
__global__ void __launch_bounds__(256)
sa_stats_part(const float* __restrict__ qp, const float* __restrict__ kp,
              float* __restrict__ psum, float* __restrict__ pmax,
              float* __restrict__ pmin, int SC) {
    const int chunk = blockIdx.x, b = blockIdx.y;
    const int e = threadIdx.x * 4;
    int base = (b * Sc + chunk * SC) * Ec + e;
    f4 s  = (f4)(0.f);
    f4 mx = (f4)(-1e30f);
    f4 mn = (f4)( 1e30f);
    for (int r = 0; r < SC; ++r, base += Ec) {
        f4 qv = feat4(*(const f4*)(qp + base));
        f4 kv = feat4(__builtin_nontemporal_load((const f4*)(kp + base)));
        s.x = fmaf(qv.x, kv.x, s.x);  mx.x = fmaxf(mx.x, qv.x);  mn.x = fminf(mn.x, qv.x);
        s.y = fmaf(qv.y, kv.y, s.y);  mx.y = fmaxf(mx.y, qv.y);  mn.y = fminf(mn.y, qv.y);
        s.z = fmaf(qv.z, kv.z, s.z);  mx.z = fmaxf(mx.z, qv.z);  mn.z = fminf(mn.z, qv.z);
        s.w = fmaf(qv.w, kv.w, s.w);  mx.w = fmaxf(mx.w, qv.w);  mn.w = fminf(mn.w, qv.w);
    }
    const int o = chunk * BEc + b * Ec + e;
    *(f4*)(psum + o) = s;
    *(f4*)(pmax + o) = mx;
    *(f4*)(pmin + o) = mn;
}

// K2a: reduce NS stats chunks -> NP parts. grid = (NP, BEc/256).
__global__ void __launch_bounds__(256)
sa_red3(const float* __restrict__ psum, const float* __restrict__ pmax,
        const float* __restrict__ pmin, float* __restrict__ psumB,
        float* __restrict__ pmaxB, float* __restrict__ pminB, int SC2) {
    const int id = blockIdx.y * 256 + threadIdx.x;
    const int p  = blockIdx.x;
    float s = 0.f, mx = -1e30f, mn = 1e30f;
    int off = p * SC2 * BEc + id;
    for (int ch = 0; ch < SC2; ++ch, off += BEc) {
        s += psum[off];
        mx = fmaxf(mx, pmax[off]);
        mn = fminf(mn, pmin[off]);
    }
    psumB[p * BEc + id] = s;
    pmaxB[p * BEc + id] = mx;
    pminB[p * BEc + id] = mn;
}

// K2b: finalize stats -> c[b,e] = colsum/32; eMax = c>=0 ? c*max : c*min
__global__ void __launch_bounds__(256)
sa_stats_fin(const float* __restrict__ psumB, const float* __restrict__ pmaxB,
             const float* __restrict__ pminB, float* __restrict__ cbuf,
             float* __restrict__ embuf) {
    const int id = blockIdx.x * blockDim.x + threadIdx.x;
    float s = 0.f, mx = -1e30f, mn = 1e30f;
#pragma unroll
    for (int p = 0; p < NP; ++p) {
        s += psumB[p * BEc + id];
        mx = fmaxf(mx, pmaxB[p * BEc + id]);
        mn = fminf(mn, pminB[p * BEc + id]);
    }
    const float c = s * (1.0f / 32.0f);   // 1/sqrt(1024)
    cbuf[id]  = c;
    embuf[id] = (c >= 0.f) ? c * mx : c * mn;
}

// K3: partial softmax denominator: sum_s exp(c*qf - eMax) over an s-chunk.
__global__ void __launch_bounds__(256)
sa_den_part(const float* __restrict__ qp, const float* __restrict__ cbuf,
            const float* __restrict__ embuf, float* __restrict__ pden, int SC) {
    const int chunk = blockIdx.x, b = blockIdx.y;
    const int e = threadIdx.x * 4;
    const f4 c4 = *(const f4*)(cbuf + b * Ec + e);
    const f4 m4 = *(const f4*)(embuf + b * Ec + e);
    int base = (b * Sc + chunk * SC) * Ec + e;
    f4 d = (f4)(0.f);
    for (int r = 0; r < SC; ++r, base += Ec) {
        f4 qv = feat4(*(const f4*)(qp + base));
        d.x += __expf(fmaf(c4.x, qv.x, -m4.x));
        d.y += __expf(fmaf(c4.y, qv.y, -m4.y));
        d.z += __expf(fmaf(c4.z, qv.z, -m4.z));
        d.w += __expf(fmaf(c4.w, qv.w, -m4.w));
    }
    const int o = chunk * BEc + b * Ec + e;
    *(f4*)(pden + o) = d;
}

// K4a: reduce NS denom chunks -> NP parts. grid = (NP, BEc/256).
__global__ void __launch_bounds__(256)
sa_red1(const float* __restrict__ pden, float* __restrict__ pdenB, int SC2) {
    const int id = blockIdx.y * 256 + threadIdx.x;
    const int p  = blockIdx.x;
    float s = 0.f;
    int off = p * SC2 * BEc + id;
    for (int ch = 0; ch < SC2; ++ch, off += BEc) s += pden[off];
    pdenB[p * BEc + id] = s;
}

// K4b: finalize denominator -> reciprocal
__global__ void __launch_bounds__(256)
sa_den_fin(const float* __restrict__ pdenB, float* __restrict__ rdbuf) {
    const int id = blockIdx.x * blockDim.x + threadIdx.x;
    float s = 0.f;
#pragma unroll
    for (int p = 0; p < NP; ++p) s += pdenB[p * BEc + id];
    rdbuf[id] = 1.0f / s;
}

// K5: out = exp(c*qf - eMax) * rdenom * values
__global__ void __launch_bounds__(256)
sa_out(const float* __restrict__ qp, const float* __restrict__ vp,
       const float* __restrict__ cbuf, const float* __restrict__ embuf,
       const float* __restrict__ rdbuf, float* __restrict__ outp, int SC) {
    const int chunk = blockIdx.x, b = blockIdx.y;
    const int e = threadIdx.x * 4;
    const f4 c4 = *(const f4*)(cbuf + b * Ec + e);
    const f4 m4 = *(const f4*)(embuf + b * Ec + e);
    const f4 r4 = *(const f4*)(rdbuf + b * Ec + e);
    int base = (b * Sc + chunk * SC) * Ec + e;
    for (int r = 0; r < SC; ++r, base += Ec) {
        f4 qv = feat4(*(const f4*)(qp + base));
        f4 vv = __builtin_nontemporal_load((const f4*)(vp + base));
        f4 o;
        o.x = __expf(fmaf(c4.x, qv.x, -m4.x)) * r4.x * vv.x;
        o.y = __expf(fmaf(c4.y, qv.y, -m4.y)) * r4.y * vv.y;
        o.z = __expf(fmaf(c4.z, qv.z, -m4.z)) * r4.z * vv.z;
        o.w = __expf(fmaf(c4.w, qv.w, -m4.w)) * r4.w * vv.w;
        __builtin_nontemporal_store(o, (f4*)(outp + base));
    }
}

extern "C" void kernel_launch(void* const* d_in, const int* in_sizes, int n_in,
                              void* d_out, int out_size, void* d_ws, size_t ws_size,
                              hipStream_t stream) {
    const float* q = (const float*)d_in[0];
    const float* k = (const float*)d_in[1];
    const float* v = (const float*)d_in[2];
    float* out = (float*)d_out;

    // pick the largest s-chunk count that fits the workspace
    int NS = 256;
    while (NS > NP &&
           (size_t)(3u * NS + 3u * NP + 3u) * BEc * sizeof(float) > ws_size)
        NS >>= 1;
    const int SC  = Sc / NS;
    const int SC2 = NS / NP;

    float* w     = (float*)d_ws;
    float* psum  = w;
    float* pmax  = psum  + (size_t)NS * BEc;
    float* pmin  = pmax  + (size_t)NS * BEc;
    float* psumB = pmin  + (size_t)NS * BEc;
    float* pmaxB = psumB + (size_t)NP * BEc;
    float* pminB = pmaxB + (size_t)NP * BEc;
    float* cbuf  = pminB + (size_t)NP * BEc;
    float* embuf = cbuf  + BEc;
    float* rdbuf = embuf + BEc;
    float* pden  = psum;    // reused after K2a
    float* pdenB = psumB;   // reused after K2b

    dim3 gridP(NS, Bc);
    dim3 gridR(NP, BEc / 256);
    sa_stats_part<<<gridP, 256, 0, stream>>>(q, k, psum, pmax, pmin, SC);
    sa_red3<<<gridR, 256, 0, stream>>>(psum, pmax, pmin, psumB, pmaxB, pminB, SC2);
    sa_stats_fin<<<BEc / 256, 256, 0, stream>>>(psumB, pmaxB, pminB, cbuf, embuf);
    sa_den_part<<<gridP, 256, 0, stream>>>(q, cbuf, embuf, pden, SC);
    sa_red1<<<gridR, 256, 0, stream>>>(pden, pdenB, SC2);
    sa_den_fin<<<BEc / 256, 256, 0, stream>>>(pdenB, rdbuf);
    sa_out<<<gridP, 256, 0, stream>>>(q, v, cbuf, embuf, rdbuf, out, SC);
}